// Round 13
// baseline (1575.945 us; speedup 1.0000x reference)
//
#include <hip/hip_runtime.h>
#include <hip/hip_bf16.h>
#include <cstdint>
#include <cstddef>

#define F_DIM 128
#define P_DIM 2048
#define RADIUS 4
#define HT_STRIDE 136   // ushorts per row: 272 B = 16B-aligned rows for b128 frag reads
#define LOG2E 1.4426950408889634f

typedef short s16x8 __attribute__((ext_vector_type(8)));
typedef float f32x4 __attribute__((ext_vector_type(4)));
typedef float f32x2 __attribute__((ext_vector_type(2)));

static __device__ __forceinline__ float bf2f(ushort u) {
    union { float f; uint i; } v; v.i = ((uint)u) << 16; return v.f;
}
static __device__ __forceinline__ ushort f2bf(float f) {
    uint u = __float_as_uint(f);
    uint r = (u + 0x7fffu + ((u >> 16) & 1u)) >> 16;   // RTN-even
    return (ushort)r;
}
// one uint holding 2 bf16 -> f32x2 {elem0, elem1} via bit ops
static __device__ __forceinline__ f32x2 bfpair(uint u) {
    union { float f; uint i; } lo, hi;
    lo.i = u << 16; hi.i = u & 0xffff0000u;
    f32x2 r; r.x = lo.f; r.y = hi.f; return r;
}
static __device__ __forceinline__ f32x4 mfma16(s16x8 a, s16x8 b, f32x4 c) {
    return __builtin_amdgcn_mfma_f32_16x16x32_bf16(a, b, c, 0, 0, 0);
}
// native v_exp_f32 / v_log_f32 (base-2). Args to ex2 are <= 0 after max-subtraction.
// R7 lesson (PINNED): logits reach hundreds+ by round 4 -- fixed-shift softmax is
// numerically INVALID; online max tracking is required.
// R11 (verified, absmax 512 < 2078): lin2 uses HI-ONLY bf16 W2 in BOTH passes ->
// pass-1/pass-2 logits bit-identical; error is within-node redistribution from W2
// quantization, inside the harness's bf16-scale threshold.
static __device__ __forceinline__ float ex2(float x) { return __builtin_amdgcn_exp2f(x); }
static __device__ __forceinline__ float lg2(float x) { return __builtin_amdgcn_logf(x); }

// ---------------- CSR build (once per launch) ----------------

__global__ void hist_kernel(const int* __restrict__ dst, int* __restrict__ counts, int E) {
    int e = blockIdx.x * blockDim.x + threadIdx.x;
    if (e < E) atomicAdd(&counts[dst[e]], 1);
}

// 3-phase parallel scan:
__global__ __launch_bounds__(1024) void scan1_kernel(const int* __restrict__ counts,
                                                     int* __restrict__ offs,
                                                     int* __restrict__ partials, int N) {
    __shared__ int buf[2][1024];
    int i = (blockIdx.x << 10) + threadIdx.x;
    int v = (i < N) ? counts[i] : 0;
    int src = 0;
    buf[0][threadIdx.x] = v;
    __syncthreads();
    for (int off = 1; off < 1024; off <<= 1) {
        int d = src ^ 1;
        int val = buf[src][threadIdx.x];
        if (threadIdx.x >= (unsigned)off) val += buf[src][threadIdx.x - off];
        buf[d][threadIdx.x] = val;
        src = d;
        __syncthreads();
    }
    int inc = buf[src][threadIdx.x];
    if (i < N) offs[i + 1] = inc;
    if (threadIdx.x == 1023) partials[blockIdx.x] = inc;
}

__global__ __launch_bounds__(1024) void scan2_kernel(int* __restrict__ partials, int nb) {
    __shared__ int buf[2][1024];
    int t = threadIdx.x;
    int v = (t < nb) ? partials[t] : 0;
    int src = 0;
    buf[0][t] = v;
    __syncthreads();
    for (int off = 1; off < 1024; off <<= 1) {
        int d = src ^ 1;
        int val = buf[src][t];
        if (t >= (unsigned)off) val += buf[src][t - off];
        buf[d][t] = val;
        src = d;
        __syncthreads();
    }
    if (t < nb) partials[t] = (t == 0) ? 0 : buf[src][t - 1];
}

__global__ void scan3_kernel(int* __restrict__ offs, const int* __restrict__ partials, int N) {
    int i = blockIdx.x * blockDim.x + threadIdx.x;
    if (i < N) offs[i + 1] += partials[i >> 10];
    if (i == 0) offs[0] = 0;
}

__global__ void copy_kernel(const int* __restrict__ offs, int* __restrict__ cursor, int N) {
    int i = blockIdx.x * blockDim.x + threadIdx.x;
    if (i < N) cursor[i] = offs[i];
}

__global__ void scatter_kernel(const int* __restrict__ src, const int* __restrict__ dst,
                               int* __restrict__ cursor, int* __restrict__ srcs_sorted, int E) {
    int e = blockIdx.x * blockDim.x + threadIdx.x;
    if (e < E) {
        int d = dst[e];
        int pos = atomicAdd(&cursor[d], 1);
        srcs_sorted[pos] = src[e];
    }
}

// ---------------- one-time converts ----------------

__global__ void cvt_bf16_kernel(const float* __restrict__ src, ushort* __restrict__ dst, int n) {
    int i = blockIdx.x * blockDim.x + threadIdx.x;
    if (i < n) dst[i] = f2bf(src[i]);
}

__global__ void scale_kernel(const float* __restrict__ src, float* __restrict__ dst,
                             int n, float scale) {
    int i = blockIdx.x * blockDim.x + threadIdx.x;
    if (i < n) dst[i] = src[i] * scale;
}

// split fp32 W[K=128][P] (times scale) into hi+lo bf16, swizzled to MFMA B-frag order:
// dst[(((pt*4 + kt)*2 + s)*64 + lane)*8 + j] = split_s(scale*W[kt*32 + (lane>>4)*8 + j][pt*16 + (lane&15)])
__global__ void swizzle_split_kernel(const float* __restrict__ src, ushort* __restrict__ dst,
                                     int P, int total, float scale) {
    int d = blockIdx.x * blockDim.x + threadIdx.x;
    if (d >= total) return;
    int j    = d & 7;
    int lane = (d >> 3) & 63;
    int s    = (d >> 9) & 1;
    int kt   = (d >> 10) & 3;
    int pt   = d >> 12;
    int k = kt * 32 + (lane >> 4) * 8 + j;
    int p = pt * 16 + (lane & 15);
    float w = src[k * P + p] * scale;
    ushort hi = f2bf(w);
    ushort out = hi;
    if (s) out = f2bf(w - bf2f(hi));
    dst[d] = out;
}

// ---------------- aggregate (bf16 in, fp32 accum, bf16 out) ----------------
// R4-verified config: 8 nodes per wave (quad owns 2 nodes), 2x-unrolled dual
// chains (4 gathers in flight/quad). R10: 4x unroll neutral -- keep 2x.

#define ACC8(acc2, u) { \
    acc2[0] += bfpair(u.x); acc2[1] += bfpair(u.y); \
    acc2[2] += bfpair(u.z); acc2[3] += bfpair(u.w); }

__global__ __launch_bounds__(256) void agg_kernel(const ushort* __restrict__ x,
                                                  const int* __restrict__ offs,
                                                  const int* __restrict__ srcs,
                                                  ushort* __restrict__ agg, int N) {
    int wid = (blockIdx.x * blockDim.x + threadIdx.x) >> 6;
    int lane = threadIdx.x & 63;
    int q = lane >> 4;
    int l16 = lane & 15;
    int n0 = wid * 8 + q;        // quad's first node
    int n1 = wid * 8 + 4 + q;    // quad's second node
    const uint4* xr = (const uint4*)x;       // 16 uint4 per row

    f32x2 accA[4], accB[4];
    #pragma unroll
    for (int i = 0; i < 4; ++i) { accA[i] = (f32x2){0.f, 0.f}; accB[i] = (f32x2){0.f, 0.f}; }
    int eA = 0, eA1 = 0, eB = 0, eB1 = 0;
    if (n0 < N) {
        uint4 v = xr[(size_t)n0 * 16 + l16];
        ACC8(accA, v);
        eA = offs[n0]; eA1 = offs[n0 + 1];
    }
    if (n1 < N) {
        uint4 v = xr[(size_t)n1 * 16 + l16];
        ACC8(accB, v);
        eB = offs[n1]; eB1 = offs[n1 + 1];
    }
    while (eA + 2 <= eA1 && eB + 2 <= eB1) {
        int ja0 = srcs[eA], ja1 = srcs[eA + 1]; eA += 2;
        int jb0 = srcs[eB], jb1 = srcs[eB + 1]; eB += 2;
        uint4 ua0 = xr[(size_t)ja0 * 16 + l16];
        uint4 ua1 = xr[(size_t)ja1 * 16 + l16];
        uint4 ub0 = xr[(size_t)jb0 * 16 + l16];
        uint4 ub1 = xr[(size_t)jb1 * 16 + l16];
        ACC8(accA, ua0); ACC8(accA, ua1);
        ACC8(accB, ub0); ACC8(accB, ub1);
    }
    while (eA < eA1 && eB < eB1) {
        int ja = srcs[eA++];
        int jb = srcs[eB++];
        uint4 ua = xr[(size_t)ja * 16 + l16];
        uint4 ub = xr[(size_t)jb * 16 + l16];
        ACC8(accA, ua);
        ACC8(accB, ub);
    }
    while (eA < eA1) {
        int ja = srcs[eA++];
        uint4 ua = xr[(size_t)ja * 16 + l16];
        ACC8(accA, ua);
    }
    while (eB < eB1) {
        int jb = srcs[eB++];
        uint4 ub = xr[(size_t)jb * 16 + l16];
        ACC8(accB, ub);
    }
    if (n0 < N) {
        uint4 o;
        o.x = ((uint)f2bf(accA[0].y) << 16) | (uint)f2bf(accA[0].x);
        o.y = ((uint)f2bf(accA[1].y) << 16) | (uint)f2bf(accA[1].x);
        o.z = ((uint)f2bf(accA[2].y) << 16) | (uint)f2bf(accA[2].x);
        o.w = ((uint)f2bf(accA[3].y) << 16) | (uint)f2bf(accA[3].x);
        ((uint4*)agg)[(size_t)n0 * 16 + l16] = o;
    }
    if (n1 < N) {
        uint4 o;
        o.x = ((uint)f2bf(accB[0].y) << 16) | (uint)f2bf(accB[0].x);
        o.y = ((uint)f2bf(accB[1].y) << 16) | (uint)f2bf(accB[1].x);
        o.z = ((uint)f2bf(accB[2].y) << 16) | (uint)f2bf(accB[2].x);
        o.w = ((uint)f2bf(accB[3].y) << 16) | (uint)f2bf(accB[3].x);
        ((uint4*)agg)[(size_t)n1 * 16 + l16] = o;
    }
}

// ---------------- fused round ----------------
// R11-verified body (209us round, absmax 512, VGPR 108): R4 structure + hi-only
// W2 in lin2. R12 hoist: neutral (load latency ruled out) -- reverted.
// R13: __launch_bounds__(256, 3). Rationale: hi-only dropped natural VGPR to 108;
// the (256,3) cap (~170) is comfortably ABOVE that (unlike R6's (256,4) cap=128
// vs need 128+, which crushed codegen to 64). Codegen should stay ~108 while
// residency rises 2 -> 3 waves/SIMD, covering the ~60us neither-pipe-issues gap
// (wave-scaling law, R4/R8). REGRESSION CHECK: VGPR must stay 104-112 and no
// scratch; if demoted, revert to (256,2).
// PINNED: online max required (R7); never cap VGPR below the pipeline's need.

#define LOADB(bb_) { _Pragma("unroll") for (int f = 0; f < 4; ++f) bb_[f] = wpn[f * 128]; wpn += 512; }

#define MFMA4(cc, bb_) { \
    _Pragma("unroll") for (int g = 0; g < 4; ++g) cc[g] = mfma16(a[g][0], bb_[0], czero); \
    _Pragma("unroll") for (int kt = 1; kt < 4; ++kt) { \
        _Pragma("unroll") for (int g = 0; g < 4; ++g) cc[g] = mfma16(a[g][kt], bb_[kt], cc[g]); } }

// packed online-softmax update: slot j2 = g*2+h covers old j = g*4+2h+{0,1}
#define P1_UPD4(cc, bbv) { \
    f32x2 bb2; bb2.x = (bbv); bb2.y = (bbv); \
    _Pragma("unroll") for (int g = 0; g < 4; ++g) \
    _Pragma("unroll") for (int h = 0; h < 2; ++h) { \
        int j2 = g * 2 + h; \
        f32x2 v; v.x = cc[g][2 * h]; v.y = cc[g][2 * h + 1]; \
        v = v + bb2; \
        f32x2 d = v - m2_[j2]; \
        f32x2 e; e.x = ex2(-fabsf(d.x)); e.y = ex2(-fabsf(d.y)); \
        f32x2 t1 = s2_[j2] + e; \
        f32x2 t2 = __builtin_elementwise_fma(s2_[j2], e, one2); \
        s2_[j2].x = d.x > 0.f ? t2.x : t1.x; \
        s2_[j2].y = d.y > 0.f ? t2.y : t1.y; \
        m2_[j2] = __builtin_elementwise_max(m2_[j2], v); \
    } }

#define P2_UPD4(cc, bbv, ptv) { \
    f32x2 bb2; bb2.x = (bbv); bb2.y = (bbv); \
    f32x2 tot2; tot2.x = 0.f; tot2.y = 0.f; \
    _Pragma("unroll") for (int g = 0; g < 4; ++g) \
    _Pragma("unroll") for (int h = 0; h < 2; ++h) { \
        f32x2 v; v.x = cc[g][2 * h]; v.y = cc[g][2 * h + 1]; \
        v = v + bb2 + bbk2[g * 2 + h]; \
        tot2.x += ex2(v.x); tot2.y += ex2(v.y); \
    } \
    float tot = tot2.x + tot2.y; \
    tot += __shfl_xor(tot, 16); \
    tot += __shfl_xor(tot, 32); \
    if (lane < 16) atomicAdd(&fp[(ptv) * 16 + lane], tot); }

__global__ __launch_bounds__(256, 3) void round_kernel(
        const ushort* __restrict__ agg,    // [N,128] bf16
        const ushort* __restrict__ w1sw,   // swizzled hi/lo bf16 (natural scale)
        const float*  __restrict__ b1,
        const ushort* __restrict__ w2sw,   // swizzled hi/lo bf16, scaled by log2e
        const float*  __restrict__ b2l,    // b2 * log2e
        ushort* __restrict__ h_out,        // [N,128] bf16 (next round x)
        float* __restrict__ fp,            // [2048]
        int N) {
    __shared__ ushort smem_u[64 * HT_STRIDE];  // 17.4 KB; hT, later (m,s) merge buf
    ushort* hT = smem_u;
    float* mbuf = (float*)smem_u;              // [64][4] after hT is dead
    float* sbuf = ((float*)smem_u) + 256;      // [64][4]

    const int tid = threadIdx.x;
    const int w = tid >> 6;
    const int lane = tid & 63;
    const int q = lane >> 4;
    const int l15 = lane & 15;
    const int nodeBase = blockIdx.x * 64;
    const int ptBase = w * 32;

    const f32x4 czero = {0.f, 0.f, 0.f, 0.f};
    f32x2 one2; one2.x = 1.0f; one2.y = 1.0f;

    const s16x8* w1v = (const s16x8*)w1sw;   // frag index: (pt*8 + kt*2 + s)*64 + lane
    const s16x8* w2v = (const s16x8*)w2sw;

    // ---- A-frags from global agg (all 4 waves load the same tile; L1-served) ----
    s16x8 a[4][4];
    #pragma unroll
    for (int g = 0; g < 4; ++g) {
        int node = nodeBase + g * 16 + l15;
        #pragma unroll
        for (int kt = 0; kt < 4; ++kt) {
            if (node < N)
                a[g][kt] = *(const s16x8*)(agg + (size_t)node * F_DIM + kt * 32 + q * 8);
            else
                a[g][kt] = (s16x8){0, 0, 0, 0, 0, 0, 0, 0};
        }
    }

    // ---- lin1: wave w computes feature tiles 2w, 2w+1 (h = relu(agg@W1+b1)) ----
    // Full hi/lo precision (h feeds all subsequent rounds).
    #pragma unroll
    for (int t = 0; t < 2; ++t) {
        int pt = 2 * w + t;
        f32x4 c[4];
        const s16x8* wp = w1v + pt * 8 * 64;
        {
            s16x8 bh = wp[0 * 64 + lane];
            s16x8 bl = wp[1 * 64 + lane];
            #pragma unroll
            for (int g = 0; g < 4; ++g) {
                c[g] = mfma16(a[g][0], bh, czero);
                c[g] = mfma16(a[g][0], bl, c[g]);
            }
        }
        #pragma unroll
        for (int kt = 1; kt < 4; ++kt) {
            s16x8 bh = wp[(kt * 2 + 0) * 64 + lane];
            s16x8 bl = wp[(kt * 2 + 1) * 64 + lane];
            #pragma unroll
            for (int g = 0; g < 4; ++g) {
                c[g] = mfma16(a[g][kt], bh, c[g]);
                c[g] = mfma16(a[g][kt], bl, c[g]);
            }
        }
        float bb = b1[pt * 16 + l15];
        #pragma unroll
        for (int g = 0; g < 4; ++g)
            #pragma unroll
            for (int r = 0; r < 4; ++r) {
                float v = c[g][r] + bb;
                v = v > 0.f ? v : 0.f;
                hT[(g * 16 + q * 4 + r) * HT_STRIDE + pt * 16 + l15] = f2bf(v);
            }
    }
    __syncthreads();

    // ---- coalesced hT -> h_out: 64 rows x 16 chunks over 256 threads ----
    #pragma unroll
    for (int it = 0; it < 4; ++it) {
        int idx = it * 256 + tid;      // 0..1023
        int row = idx >> 4;            // 0..63
        int chunk = idx & 15;          // 0..15
        int gnode = nodeBase + row;
        if (gnode < N) {
            s16x8 vv = *(const s16x8*)&hT[row * HT_STRIDE + chunk * 8];
            *(s16x8*)(h_out + (size_t)gnode * F_DIM + chunk * 8) = vv;
        }
    }

    // ---- lin2 A-frags from hT (reuse a[][]) ----
    #pragma unroll
    for (int g = 0; g < 4; ++g)
        #pragma unroll
        for (int kt = 0; kt < 4; ++kt)
            a[g][kt] = *(const s16x8*)&hT[(g * 16 + l15) * HT_STRIDE + kt * 32 + q * 8];
    __syncthreads();   // hT dead everywhere; allow (m,s) overlay

    // ---- pass 1: online max / sum-exp2 over the wave's 32 pts (pipelined, hi-only W2) ----
    f32x2 m2_[8], s2_[8];
    #pragma unroll
    for (int j = 0; j < 8; ++j) {
        m2_[j].x = -INFINITY; m2_[j].y = -INFINITY;
        s2_[j].x = 0.f;       s2_[j].y = 0.f;
    }

    {
        const s16x8* wpn = w2v + ptBase * 8 * 64 + lane;   // bump by 512/LOADB
        const float* bpn = b2l + ptBase * 16 + l15;        // bump by 16/bias
        s16x8 bA[4], bB[4];
        f32x4 cA[4], cB[4];
        float bbA, bbB;
        LOADB(bA); bbA = *bpn; bpn += 16;   // i=0
        LOADB(bB); bbB = *bpn; bpn += 16;   // i=1
        MFMA4(cA, bA);                      // c(0)
        #pragma unroll 1
        for (int k = 0; k < 15; ++k) {
            // i = 2k+1: prefetch b(2k+2); compute c(2k+1); consume c(2k)
            float bbu = bbA;
            LOADB(bA); bbA = *bpn; bpn += 16;
            MFMA4(cB, bB);
            P1_UPD4(cA, bbu);
            // i = 2k+2: prefetch b(2k+3); compute c(2k+2); consume c(2k+1)
            float bbv = bbB;
            LOADB(bB); bbB = *bpn; bpn += 16;
            MFMA4(cA, bA);
            P1_UPD4(cB, bbv);
        }
        // i = 31: compute c(31); consume c(30), then c(31)
        MFMA4(cB, bB);
        P1_UPD4(cA, bbA);
        P1_UPD4(cB, bbB);
    }

    // ---- intra-wave merge across 16 p-lanes; publish per-wave partials ----
    #pragma unroll
    for (int j = 0; j < 16; ++j) {
        int j2 = (j >> 2) * 2 + ((j >> 1) & 1);
        int cmp = j & 1;
        float mm = m2_[j2][cmp], ss = s2_[j2][cmp];
        #pragma unroll
        for (int off = 1; off <= 8; off <<= 1) {
            float om = __shfl_xor(mm, off);
            float os = __shfl_xor(ss, off);
            float nm = fmaxf(mm, om);
            ss = ss * ex2(mm - nm) + os * ex2(om - nm);
            mm = nm;
        }
        if (l15 == 0) {
            int node = (j >> 2) * 16 + q * 4 + (j & 3);
            mbuf[node * 4 + w] = mm;
            sbuf[node * 4 + w] = ss;
        }
    }
    __syncthreads();

    // ---- cross-wave merge -> bbk = -m - log2(s), packed to match P2 slots ----
    f32x2 bbk2[8];
    #pragma unroll
    for (int j = 0; j < 16; ++j) {
        int node = (j >> 2) * 16 + q * 4 + (j & 3);
        float4 mv = *(const float4*)&mbuf[node * 4];
        float4 sv = *(const float4*)&sbuf[node * 4];
        float nm = fmaxf(fmaxf(mv.x, mv.y), fmaxf(mv.z, mv.w));
        float ss = sv.x * ex2(mv.x - nm) + sv.y * ex2(mv.y - nm)
                 + sv.z * ex2(mv.z - nm) + sv.w * ex2(mv.w - nm);
        float bb = (nodeBase + node < N) ? (-nm - lg2(ss)) : -INFINITY;
        int j2 = (j >> 2) * 2 + ((j >> 1) & 1);
        bbk2[j2][j & 1] = bb;
    }

    // ---- pass 2: recompute the wave's 32 pts (pipelined, hi-only W2 -- logits
    //      bit-identical to pass 1), atomics to global fp ----
    {
        const s16x8* wpn = w2v + ptBase * 8 * 64 + lane;
        const float* bpn = b2l + ptBase * 16 + l15;
        s16x8 bA[4], bB[4];
        f32x4 cA[4], cB[4];
        float bbA, bbB;
        LOADB(bA); bbA = *bpn; bpn += 16;   // i=0
        LOADB(bB); bbB = *bpn; bpn += 16;   // i=1
        MFMA4(cA, bA);                      // c(0)
        #pragma unroll 1
        for (int k = 0; k < 15; ++k) {
            float bbu = bbA;
            LOADB(bA); bbA = *bpn; bpn += 16;
            MFMA4(cB, bB);
            P2_UPD4(cA, bbu, ptBase + 2 * k);
            float bbv = bbB;
            LOADB(bB); bbB = *bpn; bpn += 16;
            MFMA4(cA, bA);
            P2_UPD4(cB, bbv, ptBase + 2 * k + 1);
        }
        MFMA4(cB, bB);
        P2_UPD4(cA, bbA, ptBase + 30);
        P2_UPD4(cB, bbB, ptBase + 31);
    }
}

// ---------------- launcher ----------------

extern "C" void kernel_launch(void* const* d_in, const int* in_sizes, int n_in,
                              void* d_out, int out_size, void* d_ws, size_t ws_size,
                              hipStream_t stream) {
    const float* atoms = (const float*)d_in[0];
    const float* W1    = (const float*)d_in[1];
    const float* b1    = (const float*)d_in[2];
    const float* W2    = (const float*)d_in[3];
    const float* b2    = (const float*)d_in[4];
    const int* esrc    = (const int*)d_in[5];
    const int* edst    = (const int*)d_in[6];
    float* fp          = (float*)d_out;
    const int N = in_sizes[0] / F_DIM;
    const int E = in_sizes[5];

    char* ws = (char*)d_ws;
    ushort* xA   = (ushort*)ws;  ws += (size_t)N * F_DIM * sizeof(ushort);
    ushort* xB   = (ushort*)ws;  ws += (size_t)N * F_DIM * sizeof(ushort);
    ushort* aggb = (ushort*)ws;  ws += (size_t)N * F_DIM * sizeof(ushort);
    ushort* w1sw = (ushort*)ws;  ws += (size_t)F_DIM * F_DIM * 2 * sizeof(ushort);
    ushort* w2sw = (ushort*)ws;  ws += (size_t)F_DIM * P_DIM * 2 * sizeof(ushort);
    float*  b2l  = (float*)ws;   ws += (size_t)P_DIM * sizeof(float);
    int* offs    = (int*)ws;     ws += (((size_t)(N + 1) * sizeof(int) + 255) & ~255ull);
    int* cursor  = (int*)ws;     ws += (((size_t)N * sizeof(int) + 255) & ~255ull);
    int* partials = (int*)ws;    ws += 4096;   // up to 1024 scan block totals
    int* srcs    = (int*)ws;

    hipMemsetAsync(d_out, 0, (size_t)out_size * sizeof(float), stream);
    hipMemsetAsync(cursor, 0, (size_t)N * sizeof(int), stream);

    // CSR build
    int eb = (E + 255) / 256;
    hist_kernel<<<eb, 256, 0, stream>>>(edst, cursor, E);
    int nb1 = (N + 1023) >> 10;
    scan1_kernel<<<nb1, 1024, 0, stream>>>(cursor, offs, partials, N);
    scan2_kernel<<<1, 1024, 0, stream>>>(partials, nb1);
    scan3_kernel<<<(N + 255) / 256, 256, 0, stream>>>(offs, partials, N);
    copy_kernel<<<(N + 255) / 256, 256, 0, stream>>>(offs, cursor, N);
    scatter_kernel<<<eb, 256, 0, stream>>>(esrc, edst, cursor, srcs, E);

    // one-time converts
    int nconv = N * F_DIM;
    cvt_bf16_kernel<<<(nconv + 255) / 256, 256, 0, stream>>>(atoms, xA, nconv);
    int t1 = F_DIM * F_DIM * 2;
    swizzle_split_kernel<<<(t1 + 255) / 256, 256, 0, stream>>>(W1, w1sw, F_DIM, t1, 1.0f);
    int t2 = F_DIM * P_DIM * 2;
    swizzle_split_kernel<<<(t2 + 255) / 256, 256, 0, stream>>>(W2, w2sw, P_DIM, t2, LOG2E);
    scale_kernel<<<(P_DIM + 255) / 256, 256, 0, stream>>>(b2, b2l, P_DIM, LOG2E);

    const ushort* x = xA;
    ushort* xnext = xB;
    int rblocks = (N + 63) / 64;
    int ablocks = (N + 31) / 32;   // 32 nodes per 256-thread block (8/wave, 2/quad)
    for (int r = 0; r < RADIUS; ++r) {
        agg_kernel<<<ablocks, 256, 0, stream>>>(x, offs, srcs, aggb, N);
        round_kernel<<<rblocks, 256, 0, stream>>>(aggb, w1sw, b1, w2sw, b2l,
                                                  xnext, fp, N);
        x = xnext;
        xnext = (xnext == xB) ? xA : xB;
    }
}

// Round 14
// 1320.733 us; speedup vs baseline: 1.1932x; 1.1932x over previous
//
#include <hip/hip_runtime.h>
#include <hip/hip_bf16.h>
#include <cstdint>
#include <cstddef>

#define F_DIM 128
#define P_DIM 2048
#define RADIUS 4
#define HT_STRIDE 136   // ushorts per row: 272 B = 16B-aligned rows for b128 frag reads
#define LOG2E 1.4426950408889634f

typedef short s16x8 __attribute__((ext_vector_type(8)));
typedef float f32x4 __attribute__((ext_vector_type(4)));
typedef float f32x2 __attribute__((ext_vector_type(2)));

static __device__ __forceinline__ float bf2f(ushort u) {
    union { float f; uint i; } v; v.i = ((uint)u) << 16; return v.f;
}
static __device__ __forceinline__ ushort f2bf(float f) {
    uint u = __float_as_uint(f);
    uint r = (u + 0x7fffu + ((u >> 16) & 1u)) >> 16;   // RTN-even
    return (ushort)r;
}
// one uint holding 2 bf16 -> f32x2 {elem0, elem1} via bit ops
static __device__ __forceinline__ f32x2 bfpair(uint u) {
    union { float f; uint i; } lo, hi;
    lo.i = u << 16; hi.i = u & 0xffff0000u;
    f32x2 r; r.x = lo.f; r.y = hi.f; return r;
}
static __device__ __forceinline__ f32x4 mfma16(s16x8 a, s16x8 b, f32x4 c) {
    return __builtin_amdgcn_mfma_f32_16x16x32_bf16(a, b, c, 0, 0, 0);
}
// native v_exp_f32 / v_log_f32 (base-2). Args to ex2 are <= 0 after max-subtraction.
// R7 lesson (PINNED): logits reach hundreds+ by round 4 -- fixed-shift softmax is
// numerically INVALID; online max tracking is required.
// R11 (verified, absmax 512 < 2078): lin2 uses HI-ONLY bf16 W2 in BOTH passes ->
// pass-1/pass-2 logits bit-identical; error is within-node redistribution from W2
// quantization, inside the harness's bf16-scale threshold.
// LAUNCH-BOUNDS LAW (R2/R6/R8/R9/R13, five data points): hipcc's allocator
// aggressively targets the waves-per-EU budget; this pipeline needs ~108 arch
// VGPRs, and ONLY (256,2) both satisfies that and maximizes residency. (256,3)
// -> 84 VGPR + spills (R13); (256,4) -> 64 + spills (R6); no bound -> 144 (R8).
static __device__ __forceinline__ float ex2(float x) { return __builtin_amdgcn_exp2f(x); }
static __device__ __forceinline__ float lg2(float x) { return __builtin_amdgcn_logf(x); }

// ---------------- CSR build (once per launch) ----------------

__global__ void hist_kernel(const int* __restrict__ dst, int* __restrict__ counts, int E) {
    int e = blockIdx.x * blockDim.x + threadIdx.x;
    if (e < E) atomicAdd(&counts[dst[e]], 1);
}

// 3-phase parallel scan:
__global__ __launch_bounds__(1024) void scan1_kernel(const int* __restrict__ counts,
                                                     int* __restrict__ offs,
                                                     int* __restrict__ partials, int N) {
    __shared__ int buf[2][1024];
    int i = (blockIdx.x << 10) + threadIdx.x;
    int v = (i < N) ? counts[i] : 0;
    int src = 0;
    buf[0][threadIdx.x] = v;
    __syncthreads();
    for (int off = 1; off < 1024; off <<= 1) {
        int d = src ^ 1;
        int val = buf[src][threadIdx.x];
        if (threadIdx.x >= (unsigned)off) val += buf[src][threadIdx.x - off];
        buf[d][threadIdx.x] = val;
        src = d;
        __syncthreads();
    }
    int inc = buf[src][threadIdx.x];
    if (i < N) offs[i + 1] = inc;
    if (threadIdx.x == 1023) partials[blockIdx.x] = inc;
}

__global__ __launch_bounds__(1024) void scan2_kernel(int* __restrict__ partials, int nb) {
    __shared__ int buf[2][1024];
    int t = threadIdx.x;
    int v = (t < nb) ? partials[t] : 0;
    int src = 0;
    buf[0][t] = v;
    __syncthreads();
    for (int off = 1; off < 1024; off <<= 1) {
        int d = src ^ 1;
        int val = buf[src][t];
        if (t >= (unsigned)off) val += buf[src][t - off];
        buf[d][t] = val;
        src = d;
        __syncthreads();
    }
    if (t < nb) partials[t] = (t == 0) ? 0 : buf[src][t - 1];
}

__global__ void scan3_kernel(int* __restrict__ offs, const int* __restrict__ partials, int N) {
    int i = blockIdx.x * blockDim.x + threadIdx.x;
    if (i < N) offs[i + 1] += partials[i >> 10];
    if (i == 0) offs[0] = 0;
}

__global__ void copy_kernel(const int* __restrict__ offs, int* __restrict__ cursor, int N) {
    int i = blockIdx.x * blockDim.x + threadIdx.x;
    if (i < N) cursor[i] = offs[i];
}

__global__ void scatter_kernel(const int* __restrict__ src, const int* __restrict__ dst,
                               int* __restrict__ cursor, int* __restrict__ srcs_sorted, int E) {
    int e = blockIdx.x * blockDim.x + threadIdx.x;
    if (e < E) {
        int d = dst[e];
        int pos = atomicAdd(&cursor[d], 1);
        srcs_sorted[pos] = src[e];
    }
}

// ---------------- one-time converts ----------------

__global__ void cvt_bf16_kernel(const float* __restrict__ src, ushort* __restrict__ dst, int n) {
    int i = blockIdx.x * blockDim.x + threadIdx.x;
    if (i < n) dst[i] = f2bf(src[i]);
}

__global__ void scale_kernel(const float* __restrict__ src, float* __restrict__ dst,
                             int n, float scale) {
    int i = blockIdx.x * blockDim.x + threadIdx.x;
    if (i < n) dst[i] = src[i] * scale;
}

// split fp32 W[K=128][P] (times scale) into hi+lo bf16, swizzled to MFMA B-frag order:
// dst[(((pt*4 + kt)*2 + s)*64 + lane)*8 + j] = split_s(scale*W[kt*32 + (lane>>4)*8 + j][pt*16 + (lane&15)])
__global__ void swizzle_split_kernel(const float* __restrict__ src, ushort* __restrict__ dst,
                                     int P, int total, float scale) {
    int d = blockIdx.x * blockDim.x + threadIdx.x;
    if (d >= total) return;
    int j    = d & 7;
    int lane = (d >> 3) & 63;
    int s    = (d >> 9) & 1;
    int kt   = (d >> 10) & 3;
    int pt   = d >> 12;
    int k = kt * 32 + (lane >> 4) * 8 + j;
    int p = pt * 16 + (lane & 15);
    float w = src[k * P + p] * scale;
    ushort hi = f2bf(w);
    ushort out = hi;
    if (s) out = f2bf(w - bf2f(hi));
    dst[d] = out;
}

// ---------------- aggregate (bf16 in, fp32 accum, bf16 out) ----------------
// R4-verified config: 8 nodes per wave (quad owns 2 nodes), 2x-unrolled dual
// chains (4 gathers in flight/quad). R10: 4x unroll neutral -- keep 2x.

#define ACC8(acc2, u) { \
    acc2[0] += bfpair(u.x); acc2[1] += bfpair(u.y); \
    acc2[2] += bfpair(u.z); acc2[3] += bfpair(u.w); }

__global__ __launch_bounds__(256) void agg_kernel(const ushort* __restrict__ x,
                                                  const int* __restrict__ offs,
                                                  const int* __restrict__ srcs,
                                                  ushort* __restrict__ agg, int N) {
    int wid = (blockIdx.x * blockDim.x + threadIdx.x) >> 6;
    int lane = threadIdx.x & 63;
    int q = lane >> 4;
    int l16 = lane & 15;
    int n0 = wid * 8 + q;        // quad's first node
    int n1 = wid * 8 + 4 + q;    // quad's second node
    const uint4* xr = (const uint4*)x;       // 16 uint4 per row

    f32x2 accA[4], accB[4];
    #pragma unroll
    for (int i = 0; i < 4; ++i) { accA[i] = (f32x2){0.f, 0.f}; accB[i] = (f32x2){0.f, 0.f}; }
    int eA = 0, eA1 = 0, eB = 0, eB1 = 0;
    if (n0 < N) {
        uint4 v = xr[(size_t)n0 * 16 + l16];
        ACC8(accA, v);
        eA = offs[n0]; eA1 = offs[n0 + 1];
    }
    if (n1 < N) {
        uint4 v = xr[(size_t)n1 * 16 + l16];
        ACC8(accB, v);
        eB = offs[n1]; eB1 = offs[n1 + 1];
    }
    while (eA + 2 <= eA1 && eB + 2 <= eB1) {
        int ja0 = srcs[eA], ja1 = srcs[eA + 1]; eA += 2;
        int jb0 = srcs[eB], jb1 = srcs[eB + 1]; eB += 2;
        uint4 ua0 = xr[(size_t)ja0 * 16 + l16];
        uint4 ua1 = xr[(size_t)ja1 * 16 + l16];
        uint4 ub0 = xr[(size_t)jb0 * 16 + l16];
        uint4 ub1 = xr[(size_t)jb1 * 16 + l16];
        ACC8(accA, ua0); ACC8(accA, ua1);
        ACC8(accB, ub0); ACC8(accB, ub1);
    }
    while (eA < eA1 && eB < eB1) {
        int ja = srcs[eA++];
        int jb = srcs[eB++];
        uint4 ua = xr[(size_t)ja * 16 + l16];
        uint4 ub = xr[(size_t)jb * 16 + l16];
        ACC8(accA, ua);
        ACC8(accB, ub);
    }
    while (eA < eA1) {
        int ja = srcs[eA++];
        uint4 ua = xr[(size_t)ja * 16 + l16];
        ACC8(accA, ua);
    }
    while (eB < eB1) {
        int jb = srcs[eB++];
        uint4 ub = xr[(size_t)jb * 16 + l16];
        ACC8(accB, ub);
    }
    if (n0 < N) {
        uint4 o;
        o.x = ((uint)f2bf(accA[0].y) << 16) | (uint)f2bf(accA[0].x);
        o.y = ((uint)f2bf(accA[1].y) << 16) | (uint)f2bf(accA[1].x);
        o.z = ((uint)f2bf(accA[2].y) << 16) | (uint)f2bf(accA[2].x);
        o.w = ((uint)f2bf(accA[3].y) << 16) | (uint)f2bf(accA[3].x);
        ((uint4*)agg)[(size_t)n0 * 16 + l16] = o;
    }
    if (n1 < N) {
        uint4 o;
        o.x = ((uint)f2bf(accB[0].y) << 16) | (uint)f2bf(accB[0].x);
        o.y = ((uint)f2bf(accB[1].y) << 16) | (uint)f2bf(accB[1].x);
        o.z = ((uint)f2bf(accB[2].y) << 16) | (uint)f2bf(accB[2].x);
        o.w = ((uint)f2bf(accB[3].y) << 16) | (uint)f2bf(accB[3].x);
        ((uint4*)agg)[(size_t)n1 * 16 + l16] = o;
    }
}

// ---------------- fused round ----------------
// FINAL VERIFIED CONFIG (R11/R12: 209us round, absmax 512, VGPR 108, 1330us
// total). R4 structure (4 waves, wave w owns P-range [32w,32w+32), barrier-free
// pipelined inner loops) + hi-only W2 in lin2 + launch_bounds(256,2).
// Closed levers: structure (R2/R9 demote), occupancy (R5/R6/R8/R13 demote or
// spill), setprio (R3 -3%), fixed-shift softmax (R7 invalid), VALU packing
// (R4 neutral), prefetch order (R12 neutral), gather depth (R10 neutral).

#define LOADB(bb_) { _Pragma("unroll") for (int f = 0; f < 4; ++f) bb_[f] = wpn[f * 128]; wpn += 512; }

#define MFMA4(cc, bb_) { \
    _Pragma("unroll") for (int g = 0; g < 4; ++g) cc[g] = mfma16(a[g][0], bb_[0], czero); \
    _Pragma("unroll") for (int kt = 1; kt < 4; ++kt) { \
        _Pragma("unroll") for (int g = 0; g < 4; ++g) cc[g] = mfma16(a[g][kt], bb_[kt], cc[g]); } }

// packed online-softmax update: slot j2 = g*2+h covers old j = g*4+2h+{0,1}
#define P1_UPD4(cc, bbv) { \
    f32x2 bb2; bb2.x = (bbv); bb2.y = (bbv); \
    _Pragma("unroll") for (int g = 0; g < 4; ++g) \
    _Pragma("unroll") for (int h = 0; h < 2; ++h) { \
        int j2 = g * 2 + h; \
        f32x2 v; v.x = cc[g][2 * h]; v.y = cc[g][2 * h + 1]; \
        v = v + bb2; \
        f32x2 d = v - m2_[j2]; \
        f32x2 e; e.x = ex2(-fabsf(d.x)); e.y = ex2(-fabsf(d.y)); \
        f32x2 t1 = s2_[j2] + e; \
        f32x2 t2 = __builtin_elementwise_fma(s2_[j2], e, one2); \
        s2_[j2].x = d.x > 0.f ? t2.x : t1.x; \
        s2_[j2].y = d.y > 0.f ? t2.y : t1.y; \
        m2_[j2] = __builtin_elementwise_max(m2_[j2], v); \
    } }

#define P2_UPD4(cc, bbv, ptv) { \
    f32x2 bb2; bb2.x = (bbv); bb2.y = (bbv); \
    f32x2 tot2; tot2.x = 0.f; tot2.y = 0.f; \
    _Pragma("unroll") for (int g = 0; g < 4; ++g) \
    _Pragma("unroll") for (int h = 0; h < 2; ++h) { \
        f32x2 v; v.x = cc[g][2 * h]; v.y = cc[g][2 * h + 1]; \
        v = v + bb2 + bbk2[g * 2 + h]; \
        tot2.x += ex2(v.x); tot2.y += ex2(v.y); \
    } \
    float tot = tot2.x + tot2.y; \
    tot += __shfl_xor(tot, 16); \
    tot += __shfl_xor(tot, 32); \
    if (lane < 16) atomicAdd(&fp[(ptv) * 16 + lane], tot); }

__global__ __launch_bounds__(256, 2) void round_kernel(
        const ushort* __restrict__ agg,    // [N,128] bf16
        const ushort* __restrict__ w1sw,   // swizzled hi/lo bf16 (natural scale)
        const float*  __restrict__ b1,
        const ushort* __restrict__ w2sw,   // swizzled hi/lo bf16, scaled by log2e
        const float*  __restrict__ b2l,    // b2 * log2e
        ushort* __restrict__ h_out,        // [N,128] bf16 (next round x)
        float* __restrict__ fp,            // [2048]
        int N) {
    __shared__ ushort smem_u[64 * HT_STRIDE];  // 17.4 KB; hT, later (m,s) merge buf
    ushort* hT = smem_u;
    float* mbuf = (float*)smem_u;              // [64][4] after hT is dead
    float* sbuf = ((float*)smem_u) + 256;      // [64][4]

    const int tid = threadIdx.x;
    const int w = tid >> 6;
    const int lane = tid & 63;
    const int q = lane >> 4;
    const int l15 = lane & 15;
    const int nodeBase = blockIdx.x * 64;
    const int ptBase = w * 32;

    const f32x4 czero = {0.f, 0.f, 0.f, 0.f};
    f32x2 one2; one2.x = 1.0f; one2.y = 1.0f;

    const s16x8* w1v = (const s16x8*)w1sw;   // frag index: (pt*8 + kt*2 + s)*64 + lane
    const s16x8* w2v = (const s16x8*)w2sw;

    // ---- A-frags from global agg (all 4 waves load the same tile; L1-served) ----
    s16x8 a[4][4];
    #pragma unroll
    for (int g = 0; g < 4; ++g) {
        int node = nodeBase + g * 16 + l15;
        #pragma unroll
        for (int kt = 0; kt < 4; ++kt) {
            if (node < N)
                a[g][kt] = *(const s16x8*)(agg + (size_t)node * F_DIM + kt * 32 + q * 8);
            else
                a[g][kt] = (s16x8){0, 0, 0, 0, 0, 0, 0, 0};
        }
    }

    // ---- lin1: wave w computes feature tiles 2w, 2w+1 (h = relu(agg@W1+b1)) ----
    // Full hi/lo precision (h feeds all subsequent rounds).
    #pragma unroll
    for (int t = 0; t < 2; ++t) {
        int pt = 2 * w + t;
        f32x4 c[4];
        const s16x8* wp = w1v + pt * 8 * 64;
        {
            s16x8 bh = wp[0 * 64 + lane];
            s16x8 bl = wp[1 * 64 + lane];
            #pragma unroll
            for (int g = 0; g < 4; ++g) {
                c[g] = mfma16(a[g][0], bh, czero);
                c[g] = mfma16(a[g][0], bl, c[g]);
            }
        }
        #pragma unroll
        for (int kt = 1; kt < 4; ++kt) {
            s16x8 bh = wp[(kt * 2 + 0) * 64 + lane];
            s16x8 bl = wp[(kt * 2 + 1) * 64 + lane];
            #pragma unroll
            for (int g = 0; g < 4; ++g) {
                c[g] = mfma16(a[g][kt], bh, c[g]);
                c[g] = mfma16(a[g][kt], bl, c[g]);
            }
        }
        float bb = b1[pt * 16 + l15];
        #pragma unroll
        for (int g = 0; g < 4; ++g)
            #pragma unroll
            for (int r = 0; r < 4; ++r) {
                float v = c[g][r] + bb;
                v = v > 0.f ? v : 0.f;
                hT[(g * 16 + q * 4 + r) * HT_STRIDE + pt * 16 + l15] = f2bf(v);
            }
    }
    __syncthreads();

    // ---- coalesced hT -> h_out: 64 rows x 16 chunks over 256 threads ----
    #pragma unroll
    for (int it = 0; it < 4; ++it) {
        int idx = it * 256 + tid;      // 0..1023
        int row = idx >> 4;            // 0..63
        int chunk = idx & 15;          // 0..15
        int gnode = nodeBase + row;
        if (gnode < N) {
            s16x8 vv = *(const s16x8*)&hT[row * HT_STRIDE + chunk * 8];
            *(s16x8*)(h_out + (size_t)gnode * F_DIM + chunk * 8) = vv;
        }
    }

    // ---- lin2 A-frags from hT (reuse a[][]) ----
    #pragma unroll
    for (int g = 0; g < 4; ++g)
        #pragma unroll
        for (int kt = 0; kt < 4; ++kt)
            a[g][kt] = *(const s16x8*)&hT[(g * 16 + l15) * HT_STRIDE + kt * 32 + q * 8];
    __syncthreads();   // hT dead everywhere; allow (m,s) overlay

    // ---- pass 1: online max / sum-exp2 over the wave's 32 pts (pipelined, hi-only W2) ----
    f32x2 m2_[8], s2_[8];
    #pragma unroll
    for (int j = 0; j < 8; ++j) {
        m2_[j].x = -INFINITY; m2_[j].y = -INFINITY;
        s2_[j].x = 0.f;       s2_[j].y = 0.f;
    }

    {
        const s16x8* wpn = w2v + ptBase * 8 * 64 + lane;   // bump by 512/LOADB
        const float* bpn = b2l + ptBase * 16 + l15;        // bump by 16/bias
        s16x8 bA[4], bB[4];
        f32x4 cA[4], cB[4];
        float bbA, bbB;
        LOADB(bA); bbA = *bpn; bpn += 16;   // i=0
        LOADB(bB); bbB = *bpn; bpn += 16;   // i=1
        MFMA4(cA, bA);                      // c(0)
        #pragma unroll 1
        for (int k = 0; k < 15; ++k) {
            // i = 2k+1: prefetch b(2k+2); compute c(2k+1); consume c(2k)
            float bbu = bbA;
            LOADB(bA); bbA = *bpn; bpn += 16;
            MFMA4(cB, bB);
            float bbv = bbB;
            LOADB(bB); bbB = *bpn; bpn += 16;
            P1_UPD4(cA, bbu);
            MFMA4(cA, bA);
            P1_UPD4(cB, bbv);
        }
        // i = 31: compute c(31); consume c(30), then c(31)
        MFMA4(cB, bB);
        P1_UPD4(cA, bbA);
        P1_UPD4(cB, bbB);
    }

    // ---- intra-wave merge across 16 p-lanes; publish per-wave partials ----
    #pragma unroll
    for (int j = 0; j < 16; ++j) {
        int j2 = (j >> 2) * 2 + ((j >> 1) & 1);
        int cmp = j & 1;
        float mm = m2_[j2][cmp], ss = s2_[j2][cmp];
        #pragma unroll
        for (int off = 1; off <= 8; off <<= 1) {
            float om = __shfl_xor(mm, off);
            float os = __shfl_xor(ss, off);
            float nm = fmaxf(mm, om);
            ss = ss * ex2(mm - nm) + os * ex2(om - nm);
            mm = nm;
        }
        if (l15 == 0) {
            int node = (j >> 2) * 16 + q * 4 + (j & 3);
            mbuf[node * 4 + w] = mm;
            sbuf[node * 4 + w] = ss;
        }
    }
    __syncthreads();

    // ---- cross-wave merge -> bbk = -m - log2(s), packed to match P2 slots ----
    f32x2 bbk2[8];
    #pragma unroll
    for (int j = 0; j < 16; ++j) {
        int node = (j >> 2) * 16 + q * 4 + (j & 3);
        float4 mv = *(const float4*)&mbuf[node * 4];
        float4 sv = *(const float4*)&sbuf[node * 4];
        float nm = fmaxf(fmaxf(mv.x, mv.y), fmaxf(mv.z, mv.w));
        float ss = sv.x * ex2(mv.x - nm) + sv.y * ex2(mv.y - nm)
                 + sv.z * ex2(mv.z - nm) + sv.w * ex2(mv.w - nm);
        float bb = (nodeBase + node < N) ? (-nm - lg2(ss)) : -INFINITY;
        int j2 = (j >> 2) * 2 + ((j >> 1) & 1);
        bbk2[j2][j & 1] = bb;
    }

    // ---- pass 2: recompute the wave's 32 pts (pipelined, hi-only W2 -- logits
    //      bit-identical to pass 1), atomics to global fp ----
    {
        const s16x8* wpn = w2v + ptBase * 8 * 64 + lane;
        const float* bpn = b2l + ptBase * 16 + l15;
        s16x8 bA[4], bB[4];
        f32x4 cA[4], cB[4];
        float bbA, bbB;
        LOADB(bA); bbA = *bpn; bpn += 16;   // i=0
        LOADB(bB); bbB = *bpn; bpn += 16;   // i=1
        MFMA4(cA, bA);                      // c(0)
        #pragma unroll 1
        for (int k = 0; k < 15; ++k) {
            float bbu = bbA;
            LOADB(bA); bbA = *bpn; bpn += 16;
            MFMA4(cB, bB);
            float bbv = bbB;
            LOADB(bB); bbB = *bpn; bpn += 16;
            P2_UPD4(cA, bbu, ptBase + 2 * k);
            MFMA4(cA, bA);
            P2_UPD4(cB, bbv, ptBase + 2 * k + 1);
        }
        MFMA4(cB, bB);
        P2_UPD4(cA, bbA, ptBase + 30);
        P2_UPD4(cB, bbB, ptBase + 31);
    }
}

// ---------------- launcher ----------------

extern "C" void kernel_launch(void* const* d_in, const int* in_sizes, int n_in,
                              void* d_out, int out_size, void* d_ws, size_t ws_size,
                              hipStream_t stream) {
    const float* atoms = (const float*)d_in[0];
    const float* W1    = (const float*)d_in[1];
    const float* b1    = (const float*)d_in[2];
    const float* W2    = (const float*)d_in[3];
    const float* b2    = (const float*)d_in[4];
    const int* esrc    = (const int*)d_in[5];
    const int* edst    = (const int*)d_in[6];
    float* fp          = (float*)d_out;
    const int N = in_sizes[0] / F_DIM;
    const int E = in_sizes[5];

    char* ws = (char*)d_ws;
    ushort* xA   = (ushort*)ws;  ws += (size_t)N * F_DIM * sizeof(ushort);
    ushort* xB   = (ushort*)ws;  ws += (size_t)N * F_DIM * sizeof(ushort);
    ushort* aggb = (ushort*)ws;  ws += (size_t)N * F_DIM * sizeof(ushort);
    ushort* w1sw = (ushort*)ws;  ws += (size_t)F_DIM * F_DIM * 2 * sizeof(ushort);
    ushort* w2sw = (ushort*)ws;  ws += (size_t)F_DIM * P_DIM * 2 * sizeof(ushort);
    float*  b2l  = (float*)ws;   ws += (size_t)P_DIM * sizeof(float);
    int* offs    = (int*)ws;     ws += (((size_t)(N + 1) * sizeof(int) + 255) & ~255ull);
    int* cursor  = (int*)ws;     ws += (((size_t)N * sizeof(int) + 255) & ~255ull);
    int* partials = (int*)ws;    ws += 4096;   // up to 1024 scan block totals
    int* srcs    = (int*)ws;

    hipMemsetAsync(d_out, 0, (size_t)out_size * sizeof(float), stream);
    hipMemsetAsync(cursor, 0, (size_t)N * sizeof(int), stream);

    // CSR build
    int eb = (E + 255) / 256;
    hist_kernel<<<eb, 256, 0, stream>>>(edst, cursor, E);
    int nb1 = (N + 1023) >> 10;
    scan1_kernel<<<nb1, 1024, 0, stream>>>(cursor, offs, partials, N);
    scan2_kernel<<<1, 1024, 0, stream>>>(partials, nb1);
    scan3_kernel<<<(N + 255) / 256, 256, 0, stream>>>(offs, partials, N);
    copy_kernel<<<(N + 255) / 256, 256, 0, stream>>>(offs, cursor, N);
    scatter_kernel<<<eb, 256, 0, stream>>>(esrc, edst, cursor, srcs, E);

    // one-time converts
    int nconv = N * F_DIM;
    cvt_bf16_kernel<<<(nconv + 255) / 256, 256, 0, stream>>>(atoms, xA, nconv);
    int t1 = F_DIM * F_DIM * 2;
    swizzle_split_kernel<<<(t1 + 255) / 256, 256, 0, stream>>>(W1, w1sw, F_DIM, t1, 1.0f);
    int t2 = F_DIM * P_DIM * 2;
    swizzle_split_kernel<<<(t2 + 255) / 256, 256, 0, stream>>>(W2, w2sw, P_DIM, t2, LOG2E);
    scale_kernel<<<(P_DIM + 255) / 256, 256, 0, stream>>>(b2, b2l, P_DIM, LOG2E);

    const ushort* x = xA;
    ushort* xnext = xB;
    int rblocks = (N + 63) / 64;
    int ablocks = (N + 31) / 32;   // 32 nodes per 256-thread block (8/wave, 2/quad)
    for (int r = 0; r < RADIUS; ++r) {
        agg_kernel<<<ablocks, 256, 0, stream>>>(x, offs, srcs, aggb, N);
        round_kernel<<<rblocks, 256, 0, stream>>>(aggb, w1sw, b1, w2sw, b2l,
                                                  xnext, fp, N);
        x = xnext;
        xnext = (xnext == xB) ? xA : xB;
    }
}